// Round 13
// baseline (98.708 us; speedup 1.0000x reference)
//
#include <hip/hip_runtime.h>

// Sliding-window attention B=4,S=4096,D=128,|i-j|<=127, fp32 in/out.
// v8b: v8 with PST fixed 40 -> 72 (P tile is 16x64; 40 caused row overlap).
//  prep: K -> fp16 plain [b][s][d]; V -> fp16 V^T per 64-key chunk
//        [b][chunk][d][key] (plain). Both in d_ws.
//  main: one wave per (16-row q-tile x key-half). 512 blocks x 256 thr
//        (4 waves = 2 tiles x 2 key-halves). K/V B-fragments loaded
//        DIRECTLY global->VGPR (L2-resident after prep) — no LDS staging,
//        no __syncthreads in the loop. P round-trip through per-wave LDS
//        (lgkmcnt only). Fixed-base softmax p=exp(s-4); key-half merge
//        (additive) in a one-barrier epilogue.
// QK^T fp16 MFMA 2-term (Q hi/lo); PV fp16 MFMA.

typedef __attribute__((ext_vector_type(8))) _Float16 half8;
typedef __attribute__((ext_vector_type(2))) __fp16 fp16x2;
typedef __attribute__((ext_vector_type(4))) float floatx4;

#define MFMA_F16(a, b, c) __builtin_amdgcn_mfma_f32_16x16x32_f16(a, b, c, 0, 0, 0)

constexpr int S_ = 4096, D_ = 128, W_ = 127;
constexpr int PST = 72;   // Ps row stride (halfs); MUST be > 64 (P is 16x64)
constexpr int OST = 132;  // Om row stride (floats)

__device__ __forceinline__ unsigned pk2(float a, float b) {
  union { fp16x2 h; unsigned u; } c;
  c.h = __builtin_amdgcn_cvt_pkrtz(a, b);
  return c.u;
}

// ---------------- prepass: fp32 -> fp16 (plain), V chunk-transpose ----------
__global__ __launch_bounds__(256, 4)
void prep_kernel(const float* __restrict__ kg, const float* __restrict__ vg,
                 _Float16* __restrict__ K16, _Float16* __restrict__ Vt16)
{
  __shared__ __align__(16) _Float16 Vs[64 * D_];  // 16 KB
  const int t  = threadIdx.x;
  const int bb = blockIdx.x >> 6;   // batch
  const int c  = blockIdx.x & 63;   // 64-key chunk
  const size_t base = ((size_t)bb * S_ + c * 64) * D_;

  // ---- K: plain fp16 cast, coalesced ----
#pragma unroll
  for (int j = 0; j < 4; ++j) {
    const int id = t + 256 * j;          // 64 rows x 16 16B-blocks
    const int s = id >> 4, blk = id & 15;
    const float* src = kg + base + s * D_ + blk * 8;
    float4 a  = *(const float4*)src;
    float4 b2 = *(const float4*)(src + 4);
    uint4 w;
    w.x = pk2(a.x, a.y);  w.y = pk2(a.z, a.w);
    w.z = pk2(b2.x, b2.y); w.w = pk2(b2.z, b2.w);
    *(uint4*)(K16 + base + s * D_ + 8 * blk) = w;
  }

  // ---- V: register transpose -> (XOR-swizzled) LDS -> plain linear dump ----
  const int vr = t >> 5, vc = t & 31;
  float4 vf[8];
#pragma unroll
  for (int u = 0; u < 8; ++u)
    vf[u] = *(const float4*)(vg + base + (8 * vr + u) * D_ + 4 * vc);
#pragma unroll
  for (int i = 0; i < 4; ++i) {
    uint4 tv;
    tv.x = pk2(((const float*)&vf[0])[i], ((const float*)&vf[1])[i]);
    tv.y = pk2(((const float*)&vf[2])[i], ((const float*)&vf[3])[i]);
    tv.z = pk2(((const float*)&vf[4])[i], ((const float*)&vf[5])[i]);
    tv.w = pk2(((const float*)&vf[6])[i], ((const float*)&vf[7])[i]);
    const int d = 4 * vc + i;
    *(uint4*)(&Vs[d * 64 + 8 * (vr ^ (d & 7))]) = tv;
  }
  __syncthreads();
  _Float16* vdst = Vt16 + (size_t)(bb * 64 + c) * (D_ * 64);
#pragma unroll
  for (int i = 0; i < 4; ++i) {
    const int id2 = t + 256 * i;          // d*8 + keyblock
    const int d = id2 >> 3, g = id2 & 7;
    *(uint4*)(vdst + id2 * 8) = *(const uint4*)(&Vs[d * 64 + 8 * (g ^ (d & 7))]);
  }
}

// ---------------- main attention kernel (barrier-free loop) ----------------
__global__ __launch_bounds__(256, 2)
void swa_v8_kernel(const float* __restrict__ qg,
                   const _Float16* __restrict__ K16,
                   const _Float16* __restrict__ Vt16,
                   float* __restrict__ og)
{
  __shared__ __align__(16) _Float16 Ps[4][16 * PST];  //  9216 B
  __shared__ __align__(16) float    Om[4][16 * OST];  // 33792 B
  __shared__ float Ls[4][16];                         //   256 B

  const int tid  = threadIdx.x;
  const int lane = tid & 63;
  const int wave = tid >> 6;     // 0..3
  const int lx   = lane & 15;
  const int quad = lane >> 4;
  const int tile = wave & 1;     // q-tile within block (16 rows)
  const int kh   = wave >> 1;    // key-half (even/odd chunks)

  // XCD swizzle: 512 blocks -> 64 per XCD, contiguous q-ranges per XCD
  const int bid = blockIdx.x;
  const int lid = (bid & 7) * 64 + (bid >> 3);
  const int bb  = lid >> 7;             // batch (0..3)
  const int q0  = (lid & 127) * 32;     // 32 queries per block

  const float* qb = qg + (size_t)bb * S_ * D_;
  float*       ob = og + (size_t)bb * S_ * D_;
  const _Float16* Kb = K16 + (size_t)bb * S_ * D_;
  const _Float16* Vb = Vt16 + (size_t)bb * 64 * (D_ * 64);

  // ---- Q fragments: A-layout, unscaled fp16 hi/lo split ----
  const int qrow = q0 + 16 * tile + lx;
  half8 qh[4], ql[4];
#pragma unroll
  for (int ks = 0; ks < 4; ++ks) {
    const float* p = qb + (size_t)qrow * D_ + 32 * ks + 8 * quad;
#pragma unroll
    for (int j = 0; j < 8; ++j) {
      float f = p[j];
      _Float16 h = (_Float16)f;
      qh[ks][j] = h;
      ql[ks][j] = (_Float16)(f - (float)h);
    }
  }

  floatx4 o[8];
#pragma unroll
  for (int dt = 0; dt < 8; ++dt) o[dt] = (floatx4){0.f, 0.f, 0.f, 0.f};
  float lp[4] = {0.f, 0.f, 0.f, 0.f};

  const int ilo = q0 + 16 * tile, ihi = ilo + 15;
  const int kstart = (ilo > W_) ? (ilo - W_) : 0;
  int kend = ihi + W_;
  if (kend > S_ - 1) kend = S_ - 1;
  const int c0 = kstart >> 6, c1 = kend >> 6;   // 3..5 chunks

  const float C1 = 0.12751727f, C2 = -5.7707802f;  // scale*log2e, -4*log2e

  for (int c = c0 + kh; c <= c1; c += 2) {
    const _Float16* kc_ = Kb + (size_t)c * 64 * D_;
    const _Float16* vc_ = Vb + (size_t)c * (D_ * 64);

    // ---- issue ALL K and V fragment loads (32 independent, 16B each) ----
    half8 kfr[4][4];   // [ks][ct]
#pragma unroll
    for (int ks = 0; ks < 4; ++ks)
#pragma unroll
      for (int ct = 0; ct < 4; ++ct)
        kfr[ks][ct] = *(const half8*)(kc_ + (16 * ct + lx) * D_ + 32 * ks + 8 * quad);
    half8 vfr[8][2];   // [dt][half]
#pragma unroll
    for (int dt = 0; dt < 8; ++dt)
#pragma unroll
      for (int h2 = 0; h2 < 2; ++h2)
        vfr[dt][h2] = *(const half8*)(vc_ + (16 * dt + lx) * 64 + 32 * h2 + 8 * quad);

    // ---- S = Q K^T : 4 key-tiles x 4 k-steps x 2 split terms ----
    floatx4 acc[4];
#pragma unroll
    for (int ct = 0; ct < 4; ++ct) acc[ct] = (floatx4){0.f, 0.f, 0.f, 0.f};
#pragma unroll
    for (int ks = 0; ks < 4; ++ks)
#pragma unroll
      for (int ct = 0; ct < 4; ++ct) {
        acc[ct] = MFMA_F16(qh[ks], kfr[ks][ct], acc[ct]);
        acc[ct] = MFMA_F16(ql[ks], kfr[ks][ct], acc[ct]);
      }

    // ---- fixed-base masked softmax ----
    const int kc = c * 64;
    const int ibase = q0 + 16 * tile + 4 * quad;
#pragma unroll
    for (int r = 0; r < 4; ++r) {
      const int i = ibase + r;
      float psum = 0.f;
#pragma unroll
      for (int ct = 0; ct < 4; ++ct) {
        const int col = kc + 16 * ct + lx;
        const bool v = (unsigned)(col - i + W_) <= (unsigned)(2 * W_);
        const float e = __builtin_amdgcn_exp2f(__builtin_fmaf(acc[ct][r], C1, C2));
        const float p = v ? e : 0.f;
        psum += p;
        Ps[wave][(4 * quad + r) * PST + 16 * ct + lx] = (_Float16)p;
      }
      lp[r] += psum;
    }
    // same-wave cross-lane RAW through LDS (per-wave region; no barrier)
    asm volatile("s_waitcnt lgkmcnt(0)" ::: "memory");
    half8 pa0 = *(const half8*)(&Ps[wave][lx * PST + 8 * quad]);
    half8 pa1 = *(const half8*)(&Ps[wave][lx * PST + 32 + 8 * quad]);

    // ---- O += P V : 8 d-tiles x 2 k-halves ----
#pragma unroll
    for (int dt = 0; dt < 8; ++dt) {
      o[dt] = MFMA_F16(pa0, vfr[dt][0], o[dt]);
      o[dt] = MFMA_F16(pa1, vfr[dt][1], o[dt]);
    }
  }

  // ---- per-wave l reduce (16 lanes per row) ----
#pragma unroll
  for (int r = 0; r < 4; ++r) {
    float s = lp[r];
    s += __shfl_xor(s, 1);
    s += __shfl_xor(s, 2);
    s += __shfl_xor(s, 4);
    s += __shfl_xor(s, 8);
    lp[r] = s;
  }

  // ---- epilogue: write raw (O,l), one barrier, merge key-halves, store ----
#pragma unroll
  for (int dt = 0; dt < 8; ++dt)
#pragma unroll
    for (int r = 0; r < 4; ++r)
      Om[wave][(4 * quad + r) * OST + 16 * dt + lx] = o[dt][r];
  if (lx == 0) {
#pragma unroll
    for (int r = 0; r < 4; ++r) Ls[wave][4 * quad + r] = lp[r];
  }
  __syncthreads();

  // 256 threads: row = tid>>3 (0..31), 16-col segment = tid&7
  const int row = tid >> 3, cd = tid & 7;
  const int tl = row >> 4, r16 = row & 15;     // tile, row within tile
  const float inv = 1.f / (Ls[tl][r16] + Ls[tl + 2][r16]);
  const float* Oa = &Om[tl][r16 * OST + 16 * cd];
  const float* Ob = &Om[tl + 2][r16 * OST + 16 * cd];
  float* dst = ob + (size_t)(q0 + row) * D_ + 16 * cd;
#pragma unroll
  for (int t = 0; t < 4; ++t) {
    float4 xa = *(const float4*)(Oa + 4 * t);
    float4 xb = *(const float4*)(Ob + 4 * t);
    float4 r4;
    r4.x = (xa.x + xb.x) * inv;
    r4.y = (xa.y + xb.y) * inv;
    r4.z = (xa.z + xb.z) * inv;
    r4.w = (xa.w + xb.w) * inv;
    *(float4*)(dst + 4 * t) = r4;
  }
}

extern "C" void kernel_launch(void* const* d_in, const int* in_sizes, int n_in,
                              void* d_out, int out_size, void* d_ws, size_t ws_size,
                              hipStream_t stream) {
  const float* q = (const float*)d_in[0];
  const float* k = (const float*)d_in[1];
  const float* v = (const float*)d_in[2];
  float* out = (float*)d_out;

  const int B = in_sizes[0] / (S_ * D_);   // 4
  _Float16* K16  = (_Float16*)d_ws;                       // 4 MB
  _Float16* Vt16 = (_Float16*)d_ws + (size_t)B * S_ * D_; // 4 MB

  prep_kernel<<<dim3(B * 64), dim3(256), 0, stream>>>(k, v, K16, Vt16);
  swa_v8_kernel<<<dim3(B * 128), dim3(256), 0, stream>>>(q, K16, Vt16, out);
}

// Round 14
// 92.191 us; speedup vs baseline: 1.0707x; 1.0707x over previous
//
#include <hip/hip_runtime.h>

// Sliding-window attention B=4,S=4096,D=128,|i-j|<=127, fp32 in/out.
// v9: prep (v6b's, swizzled fp16) + BK=128 main.
//  prep: K -> fp16 [b][s][16B-blk ^ (s&7)]; V -> fp16 V^T per 64-key chunk
//        [d][key-blk ^ (d&7)]. Both in d_ws.
//  main: 256 thr = 4 waves = 4 q-tiles (BQ=64). BK=128 -> ~3 iters/block.
//        Single-buffer LDS (83 KB), staging via linear global_load_lds 16B.
//        Per iter: issue 16 gll/thread -> vmcnt(0)+s_barrier -> compute ->
//        __syncthreads. QK^T fp16 SINGLE-term; PV fp16.
//        Fixed-base softmax p=exp(s-4); per-wave l; no cross-wave merge.

typedef __attribute__((ext_vector_type(8))) _Float16 half8;
typedef __attribute__((ext_vector_type(2))) __fp16 fp16x2;
typedef __attribute__((ext_vector_type(4))) float floatx4;

#define MFMA_F16(a, b, c) __builtin_amdgcn_mfma_f32_16x16x32_f16(a, b, c, 0, 0, 0)

constexpr int S_ = 4096, D_ = 128, W_ = 127;
constexpr int BQ = 64, BK = 128;
constexpr int PST = 136;  // Ps row stride (halfs); P tile is 16x128
constexpr int OST = 132;  // Om row stride (floats)

union SMem {
  struct {
    _Float16 Kh[BK * D_];      // 32768 B  K fp16 [key][16B-blk ^ (key&7)]
    _Float16 Vs[2 * 64 * D_];  // 32768 B  two 64-chunk V^T blocks
    _Float16 Ps[4][16 * PST];  // 17408 B  P per wave/q-tile
  } a;                         // 82944 B -> 1 block/CU (grid 256 = 1/CU)
  struct {
    float Om[4][16 * OST];     // 33792 B
  } b;
};

__device__ __forceinline__ unsigned pk2(float a, float b) {
  union { fp16x2 h; unsigned u; } c;
  c.h = __builtin_amdgcn_cvt_pkrtz(a, b);
  return c.u;
}

__device__ __forceinline__ void gll16(const _Float16* g, _Float16* l) {
  __builtin_amdgcn_global_load_lds(
      (const __attribute__((address_space(1))) void*)g,
      (__attribute__((address_space(3))) void*)l, 16, 0, 0);
}

// ---------------- prepass (v6b, proven): fp32 -> fp16, swizzle, V^T --------
__global__ __launch_bounds__(256, 4)
void prep_kernel(const float* __restrict__ kg, const float* __restrict__ vg,
                 _Float16* __restrict__ K16, _Float16* __restrict__ Vt16)
{
  __shared__ __align__(16) _Float16 Vsh[64 * D_];  // 16 KB
  const int t  = threadIdx.x;
  const int bb = blockIdx.x >> 6;   // batch
  const int c  = blockIdx.x & 63;   // 64-key chunk
  const size_t base = ((size_t)bb * S_ + c * 64) * D_;

  // ---- K: convert + in-row swizzle (blk' = blk ^ (s&7)) ----
#pragma unroll
  for (int j = 0; j < 4; ++j) {
    const int id = t + 256 * j;          // 64 rows x 16 blocks
    const int s = id >> 4, blk = id & 15;
    const float* src = kg + base + s * D_ + blk * 8;
    float4 a  = *(const float4*)src;
    float4 b2 = *(const float4*)(src + 4);
    uint4 w;
    w.x = pk2(a.x, a.y);  w.y = pk2(a.z, a.w);
    w.z = pk2(b2.x, b2.y); w.w = pk2(b2.z, b2.w);
    *(uint4*)(K16 + base + s * D_ + 8 * (blk ^ (s & 7))) = w;
  }

  // ---- V: register transpose -> swizzled LDS -> linear global dump ----
  const int vr = t >> 5, vc = t & 31;
  float4 vf[8];
#pragma unroll
  for (int u = 0; u < 8; ++u)
    vf[u] = *(const float4*)(vg + base + (8 * vr + u) * D_ + 4 * vc);
#pragma unroll
  for (int i = 0; i < 4; ++i) {
    uint4 tv;
    tv.x = pk2(((const float*)&vf[0])[i], ((const float*)&vf[1])[i]);
    tv.y = pk2(((const float*)&vf[2])[i], ((const float*)&vf[3])[i]);
    tv.z = pk2(((const float*)&vf[4])[i], ((const float*)&vf[5])[i]);
    tv.w = pk2(((const float*)&vf[6])[i], ((const float*)&vf[7])[i]);
    const int d = 4 * vc + i;
    *(uint4*)(&Vsh[d * 64 + 8 * (vr ^ (d & 7))]) = tv;
  }
  __syncthreads();
  _Float16* vdst = Vt16 + (size_t)(bb * 64 + c) * (D_ * 64);
#pragma unroll
  for (int i = 0; i < 4; ++i) {
    const int id2 = t + 256 * i;
    *(uint4*)(vdst + id2 * 8) = *(const uint4*)(&Vsh[id2 * 8]);
  }
}

// ---------------- main attention kernel (BK=128) ----------------
__global__ __launch_bounds__(256, 1)
void swa_v9_kernel(const float* __restrict__ qg,
                   const _Float16* __restrict__ K16,
                   const _Float16* __restrict__ Vt16,
                   float* __restrict__ og)
{
  __shared__ __align__(16) SMem sm;
  const int tid  = threadIdx.x;
  const int lane = tid & 63;
  const int wave = tid >> 6;     // 0..3 = q-tile
  const int lx   = lane & 15;
  const int quad = lane >> 4;

  // XCD swizzle: 256 blocks -> 32 per XCD, contiguous q-ranges per XCD
  const int bid = blockIdx.x;
  const int lid = (bid & 7) * 32 + (bid >> 3);
  const int bb  = lid >> 6;
  const int q0  = (lid & 63) * BQ;

  const float* qb = qg + (size_t)bb * S_ * D_;
  float*       ob = og + (size_t)bb * S_ * D_;
  const _Float16* Kb = K16 + (size_t)bb * S_ * D_;
  const _Float16* Vb = Vt16 + (size_t)bb * 64 * (D_ * 64);

  // ---- Q fragments: A-layout, single fp16 (rounded) ----
  const int qrow = q0 + 16 * wave + lx;
  half8 qh[4];
#pragma unroll
  for (int ks = 0; ks < 4; ++ks) {
    const float* p = qb + (size_t)qrow * D_ + 32 * ks + 8 * quad;
#pragma unroll
    for (int j = 0; j < 8; ++j) qh[ks][j] = (_Float16)p[j];
  }

  floatx4 o[8];
#pragma unroll
  for (int dt = 0; dt < 8; ++dt) o[dt] = (floatx4){0.f, 0.f, 0.f, 0.f};
  float lp[4] = {0.f, 0.f, 0.f, 0.f};

  const int ilo = q0 + 16 * wave, ihi = ilo + 15;
  const int kstart = (q0 > W_) ? (q0 - W_) : 0;
  int kend = q0 + BQ - 1 + W_;
  if (kend > S_ - 1) kend = S_ - 1;
  const int c0 = kstart >> 7, c1 = kend >> 7;   // 128-key chunks, ~3 iters

  const float C1 = 0.12751727f, C2 = -5.7707802f;  // scale*log2e, -4*log2e

  for (int c = c0; c <= c1; ++c) {
    // ---- stage 64 KB: waves 0-1 copy K (32 KB), waves 2-3 copy V (32 KB) ----
    if (wave < 2) {
      const _Float16* kcb = Kb + (size_t)c * BK * D_;
#pragma unroll
      for (int i = 0; i < 16; ++i) {
        const int seg = (wave * 16 + i) * 512;      // 1 KB segments
        gll16(kcb + seg + lane * 8, &sm.a.Kh[seg]);
      }
    } else {
      const _Float16* vcb = Vb + (size_t)(2 * c) * (64 * D_);  // 2 chunks contiguous
#pragma unroll
      for (int i = 0; i < 16; ++i) {
        const int seg = ((wave - 2) * 16 + i) * 512;
        gll16(vcb + seg + lane * 8, &sm.a.Vs[seg]);
      }
    }
    asm volatile("s_waitcnt vmcnt(0)" ::: "memory");
    __builtin_amdgcn_s_barrier();
    asm volatile("" ::: "memory");

    // ---- S = Q K^T : 8 key-tiles x 4 k-steps, single term ----
    floatx4 acc[8];
#pragma unroll
    for (int ct = 0; ct < 8; ++ct) acc[ct] = (floatx4){0.f, 0.f, 0.f, 0.f};
#pragma unroll
    for (int ks = 0; ks < 4; ++ks) {
      const int blk = 8 * ((4 * ks + quad) ^ (lx & 7));
#pragma unroll
      for (int ct = 0; ct < 8; ++ct) {
        half8 bfr = *(const half8*)(&sm.a.Kh[(16 * ct + lx) * D_ + blk]);
        acc[ct] = MFMA_F16(qh[ks], bfr, acc[ct]);
      }
    }

    // ---- fixed-base masked softmax ----
    const int kc = c * BK;
    const int ibase = q0 + 16 * wave + 4 * quad;
#pragma unroll
    for (int r = 0; r < 4; ++r) {
      const int i = ibase + r;
      float psum = 0.f;
#pragma unroll
      for (int ct = 0; ct < 8; ++ct) {
        const int col = kc + 16 * ct + lx;
        const bool v = (unsigned)(col - i + W_) <= (unsigned)(2 * W_);
        const float e = __builtin_amdgcn_exp2f(__builtin_fmaf(acc[ct][r], C1, C2));
        const float p = v ? e : 0.f;
        psum += p;
        sm.a.Ps[wave][(4 * quad + r) * PST + 16 * ct + lx] = (_Float16)p;
      }
      lp[r] += psum;
    }
    // same-wave cross-lane RAW through LDS (per-wave region)
    asm volatile("s_waitcnt lgkmcnt(0)" ::: "memory");
    half8 pa[4];
#pragma unroll
    for (int kq = 0; kq < 4; ++kq)
      pa[kq] = *(const half8*)(&sm.a.Ps[wave][lx * PST + 32 * kq + 8 * quad]);

    // ---- O += P V : 8 d-tiles x 4 key-quarters ----
#pragma unroll
    for (int dt = 0; dt < 8; ++dt) {
      const int d = 16 * dt + lx;
#pragma unroll
      for (int kq = 0; kq < 4; ++kq) {
        const int h = kq >> 1;                         // which 64-chunk
        const int kb = 4 * (kq & 1) + quad;            // key-block within it
        half8 vfr = *(const half8*)(
            &sm.a.Vs[h * (64 * D_) + d * 64 + 8 * (kb ^ (d & 7))]);
        o[dt] = MFMA_F16(pa[kq], vfr, o[dt]);
      }
    }
    __syncthreads();   // all LDS readers done before next iter's staging
  }

  // ---- per-wave l reduce + normalize ----
  float inv[4];
#pragma unroll
  for (int r = 0; r < 4; ++r) {
    float s = lp[r];
    s += __shfl_xor(s, 1);
    s += __shfl_xor(s, 2);
    s += __shfl_xor(s, 4);
    s += __shfl_xor(s, 8);
    inv[r] = 1.f / s;
  }

  // ---- epilogue: LDS transpose (normalized), coalesced float4 stores ----
#pragma unroll
  for (int dt = 0; dt < 8; ++dt)
#pragma unroll
    for (int r = 0; r < 4; ++r)
      sm.b.Om[wave][(4 * quad + r) * OST + 16 * dt + lx] = o[dt][r] * inv[r];
  __syncthreads();

  // 256 threads: row = tid>>2 (0..63), 32-col segment = tid&3
  const int row = tid >> 2, seg = tid & 3;
  const int tl = row >> 4, r16 = row & 15;
  const float* src = &sm.b.Om[tl][r16 * OST + 32 * seg];
  float* dst = ob + (size_t)(q0 + row) * D_ + 32 * seg;
#pragma unroll
  for (int t = 0; t < 8; ++t)
    *(float4*)(dst + 4 * t) = *(const float4*)(src + 4 * t);
}

extern "C" void kernel_launch(void* const* d_in, const int* in_sizes, int n_in,
                              void* d_out, int out_size, void* d_ws, size_t ws_size,
                              hipStream_t stream) {
  const float* q = (const float*)d_in[0];
  const float* k = (const float*)d_in[1];
  const float* v = (const float*)d_in[2];
  float* out = (float*)d_out;

  const int B = in_sizes[0] / (S_ * D_);   // 4
  _Float16* K16  = (_Float16*)d_ws;                       // 4 MB
  _Float16* Vt16 = (_Float16*)d_ws + (size_t)B * S_ * D_; // 4 MB

  prep_kernel<<<dim3(B * 64), dim3(256), 0, stream>>>(k, v, K16, Vt16);
  swa_v9_kernel<<<dim3(B * (S_ / BQ)), dim3(256), 0, stream>>>(q, K16, Vt16, out);
}